// Round 3
// baseline (97.561 us; speedup 1.0000x reference)
//
#include <hip/hip_runtime.h>
#include <hip/hip_bf16.h>

#define N_CODECS 1024
#define EPS 1e-8f
#define HIST_BLOCKS 1024
#define CHUNKS 16              // stage-2: 16 blocks, each sums 64 partial rows

// ws layout:
//   gpart : u16 [HIST_BLOCKS][N_CODECS]      = 2 MB   (stored as packed uint)
//   p2    : u32 [CHUNKS][N_CODECS]           = 64 KB
//   done  : u32                              = 4 B

// ---------------------------------------------------------------------------
// Kernel 1: per-block LDS histogram -> packed u16 partial (plain stores only).
// Also re-initializes the done-counter for kernel 2 (block 0), which is safe
// because kernel 2 only launches after this kernel fully completes.
// ---------------------------------------------------------------------------
__global__ void __launch_bounds__(256) hist_partial_kernel(
        const int* __restrict__ idx,
        unsigned int* __restrict__ gpart_u32,   // [HIST_BLOCKS][N_CODECS/2]
        unsigned int* __restrict__ done,
        int n4) {
    __shared__ unsigned int lcounts[N_CODECS];
    #pragma unroll
    for (int i = threadIdx.x; i < N_CODECS; i += 256) lcounts[i] = 0u;
    if (blockIdx.x == 0 && threadIdx.x == 0) *done = 0u;
    __syncthreads();

    const int4* __restrict__ idx4 = (const int4*)idx;
    int stride = gridDim.x * 256;
    for (int i = blockIdx.x * 256 + threadIdx.x; i < n4; i += stride) {
        int4 v = idx4[i];
        atomicAdd(&lcounts[v.x], 1u);   // LDS atomics only
        atomicAdd(&lcounts[v.y], 1u);
        atomicAdd(&lcounts[v.z], 1u);
        atomicAdd(&lcounts[v.w], 1u);
    }
    __syncthreads();

    // pack two bins per uint; per-block max count = 16384 < 65536, no overflow
    unsigned int* __restrict__ mypart = gpart_u32 + (size_t)blockIdx.x * (N_CODECS / 2);
    #pragma unroll
    for (int i = 0; i < 2; ++i) {
        int c = i * 256 + threadIdx.x;             // uint column 0..511
        mypart[c] = lcounts[2 * c] | (lcounts[2 * c + 1] << 16);
    }
}

// ---------------------------------------------------------------------------
// Kernel 2 (fused reduce + finalize): 16 blocks x 256 threads.
// Block c sums partial rows [c*64, c*64+64) into p2[c][*]; the last block to
// finish (device-scope done-counter) computes the entropy + perplexity.
// ---------------------------------------------------------------------------
__global__ void __launch_bounds__(256) reduce_finalize_kernel(
        const unsigned int* __restrict__ gpart_u32,  // [HIST_BLOCKS][512]
        unsigned int* __restrict__ p2,               // [CHUNKS][N_CODECS]
        unsigned int* __restrict__ done,
        float* __restrict__ out,
        float invN) {
    const int c = blockIdx.x;
    const int t = threadIdx.x;
    const unsigned int* __restrict__ base = gpart_u32 + (size_t)(c * 64) * 512;

    unsigned int s0lo = 0, s0hi = 0, s1lo = 0, s1hi = 0;
    #pragma unroll 4
    for (int k = 0; k < 64; ++k) {
        unsigned int v0 = base[(size_t)k * 512 + t];
        unsigned int v1 = base[(size_t)k * 512 + 256 + t];
        s0lo += v0 & 0xFFFFu;  s0hi += v0 >> 16;
        s1lo += v1 & 0xFFFFu;  s1hi += v1 >> 16;
    }
    // col t -> bins (2t, 2t+1); col 256+t -> bins (512+2t, 512+2t+1)
    p2[c * N_CODECS + 2 * t]           = s0lo;
    p2[c * N_CODECS + 2 * t + 1]       = s0hi;
    p2[c * N_CODECS + 512 + 2 * t]     = s1lo;
    p2[c * N_CODECS + 512 + 2 * t + 1] = s1hi;

    __threadfence();       // release: make p2 stores device-visible
    __syncthreads();       // all threads of this block done before signaling

    __shared__ bool amLast;
    if (t == 0) {
        unsigned int prev = atomicAdd(done, 1u);   // device-scope
        amLast = (prev == (unsigned int)(gridDim.x - 1));
    }
    __syncthreads();
    if (!amLast) return;

    __threadfence();       // acquire: see all other blocks' p2 stores

    float local = 0.0f;
    #pragma unroll
    for (int i = 0; i < N_CODECS / 256; ++i) {
        int b = i * 256 + t;
        unsigned int cnt = 0;
        #pragma unroll
        for (int ch = 0; ch < CHUNKS; ++ch) cnt += p2[ch * N_CODECS + b];
        float p = (float)cnt * invN;
        local += p * __logf(p + EPS);
    }

    #pragma unroll
    for (int off = 32; off > 0; off >>= 1) local += __shfl_down(local, off, 64);

    __shared__ float wsum[4];
    int wave = t >> 6, lane = t & 63;
    if (lane == 0) wsum[wave] = local;
    __syncthreads();
    if (t == 0) out[0] = __expf(-(wsum[0] + wsum[1] + wsum[2] + wsum[3]));
}

extern "C" void kernel_launch(void* const* d_in, const int* in_sizes, int n_in,
                              void* d_out, int out_size, void* d_ws, size_t ws_size,
                              hipStream_t stream) {
    const int* indices = (const int*)d_in[0];
    int n = in_sizes[0];             // 16 * 1048576 = 16,777,216
    float* out = (float*)d_out;

    unsigned int* gpart = (unsigned int*)d_ws;                          // 2 MB (packed u16)
    unsigned int* p2    = gpart + (size_t)HIST_BLOCKS * (N_CODECS / 2); // 64 KB
    unsigned int* done  = p2 + (size_t)CHUNKS * N_CODECS;               // 4 B

    int n4 = n >> 2;

    hist_partial_kernel<<<HIST_BLOCKS, 256, 0, stream>>>(indices, gpart, done, n4);
    reduce_finalize_kernel<<<CHUNKS, 256, 0, stream>>>(gpart, p2, done, out,
                                                       1.0f / (float)n);
}